// Round 1
// baseline (125.455 us; speedup 1.0000x reference)
//
#include <hip/hip_runtime.h>
#include <cstdint>
#include <utility>

#define NW 10
#define NL 4

// ============================================================================
// Round 15: resubmission of the r13/r14 champion (122.4 us in prior session).
// Previous round's bench failed on infra (container failed twice) -> no
// counters. This run re-establishes baseline timing + rocprof in-session.
//  - CNOT rings tracked as compile-time GF(2) index maps (round 2).
//  - Lightcone: layer3 keeps Rot{1,5,9}, layer2 drops Rot(7) (round 2).
//  - Product-state init folds encoding RYs + all layer-0 Rots (round 3).
//  - DPP / ds_swizzle / ds_bpermute cross-lane exchange (rounds 4,6).
//  - Sample-pair v2 packing (round 7), GF(2) basis relabeling (round 11).
//  - Engine-interleaved gate order (round 13).
//  - SGPR coefficient path via 1-block prep kernel into d_ws (round 14).
// ============================================================================

typedef float v2 __attribute__((ext_vector_type(2)));

// ---- compile-time GF(2) relabeling ----------------------------------------
struct Cols10 { unsigned c[10]; };
struct Rows10 { unsigned r[10]; };

constexpr Cols10 TMAT = {{
    0x001, 0x002, 0x004, 0x008,                  // logical 0..3 -> slot bits
    0x070, 0x080, 0x100, 0x130, 0x210, 0x200     // logical 4..9 -> lane mixes
}};

constexpr unsigned tmap(unsigned m) {
    unsigned r = 0;
    for (int b = 0; b < 10; ++b) if ((m >> b) & 1u) r ^= TMAT.c[b];
    return r;
}

constexpr Rows10 invertT() {
    unsigned a[10] = {}, inv[10] = {};
    for (int i = 0; i < 10; ++i) {
        for (int j = 0; j < 10; ++j) a[i] |= ((TMAT.c[j] >> i) & 1u) << j;
        inv[i] = 1u << i;
    }
    for (int col = 0; col < 10; ++col) {
        int piv = -1;
        for (int r2 = col; r2 < 10; ++r2) if ((a[r2] >> col) & 1u) { piv = r2; break; }
        unsigned ta = a[piv]; a[piv] = a[col]; a[col] = ta;
        unsigned ti = inv[piv]; inv[piv] = inv[col]; inv[col] = ti;
        for (int r2 = 0; r2 < 10; ++r2)
            if (r2 != col && ((a[r2] >> col) & 1u)) { a[r2] ^= a[col]; inv[r2] ^= inv[col]; }
    }
    Rows10 R{};
    for (int i = 0; i < 10; ++i) R.r[i] = inv[i];
    return R;
}
constexpr Rows10 RROW = invertT();

constexpr unsigned rmap(unsigned rowmask) {
    unsigned r = 0;
    for (int b = 0; b < 10; ++b) if ((rowmask >> b) & 1u) r ^= RROW.r[b];
    return r;
}

static_assert(RROW.r[0] == 1 && RROW.r[1] == 2 && RROW.r[2] == 4 && RROW.r[3] == 8, "slot rows");
static_assert((RROW.r[4] & 15) == 0 && (RROW.r[5] & 15) == 0 && (RROW.r[6] & 15) == 0 &&
              (RROW.r[7] & 15) == 0 && (RROW.r[8] & 15) == 0 && (RROW.r[9] & 15) == 0, "lane rows");

struct Plan {
    int n;
    uint16_t pmask[40];
    uint16_t rmask[40];
    uint8_t  lw[40];
    uint16_t measmask;
};

constexpr bool keep_rot(int l, int w) {
    if (l <= 1) return true;
    if (l == 2) return w != 7;
    return w == 1 || w == 5 || w == 9;   // l == 3
}

constexpr int engine_class(unsigned pm) {    // 0 = local, 1 = DPP, 2 = DS
    const unsigned lm = pm >> 4;
    if (lm == 0) return 0;
    if (lm == 1 || lm == 2 || lm == 3 || lm == 7 || lm == 15) return 1;
    return 2;
}

constexpr Plan make_plan() {
    Plan P{};
    unsigned row[10], cI[10];
    for (int b = 0; b < 10; ++b) { row[b] = 1u << b; cI[b] = 1u << b; }
    P.n = 0;
    for (int l = 0; l < NL; ++l) {
        unsigned pm[10] = {}, rm[10] = {};
        int lw[10] = {}, cls[10] = {}, cnt = 0;
        for (int w = 0; w < NW; ++w) {
            if (l > 0 && keep_rot(l, w)) {
                const int b = 9 - w;
                pm[cnt] = tmap(cI[b]);
                rm[cnt] = rmap(row[b]);
                lw[cnt] = l * NW + w;
                cls[cnt] = engine_class(pm[cnt]);
                cnt++;
            }
        }
        // interleave DS gates with non-DS gates (alternating pipe bursts)
        int dsIdx[10] = {}, otIdx[10] = {};
        int nds = 0, not_ = 0;
        for (int i = 0; i < cnt; ++i) {
            if (cls[i] == 2) dsIdx[nds++] = i; else otIdx[not_++] = i;
        }
        int di = 0, oi = 0;
        while (di < nds || oi < not_) {
            if (di < nds) {
                const int i = dsIdx[di++];
                P.pmask[P.n] = (uint16_t)pm[i];
                P.rmask[P.n] = (uint16_t)rm[i];
                P.lw[P.n]    = (uint8_t)lw[i];
                P.n++;
            }
            if (oi < not_) {
                const int i = otIdx[oi++];
                P.pmask[P.n] = (uint16_t)pm[i];
                P.rmask[P.n] = (uint16_t)rm[i];
                P.lw[P.n]    = (uint8_t)lw[i];
                P.n++;
            }
        }
        const int r = l % (NW - 1) + 1;
        for (int w = 0; w < NW; ++w) {              // ring: CNOT(w, (w+r)%10)
            const int cb = 9 - w, tb = 9 - ((w + r) % NW);
            row[tb] ^= row[cb];                     // M <- C * M
            cI[cb]  ^= cI[tb];                      // Minv <- Minv * C
        }
    }
    P.measmask = (uint16_t)rmap(row[0]);            // Z on virtual bit 0 (wire 9)
    return P;
}

constexpr Plan PL = make_plan();
constexpr int NROT = 22;
static_assert(PL.n == NROT, "plan size mismatch");

constexpr int LSEL[6] = {
    (int)(RROW.r[9] >> 4), (int)(RROW.r[8] >> 4), (int)(RROW.r[7] >> 4),
    (int)(RROW.r[6] >> 4), (int)(RROW.r[5] >> 4), (int)(RROW.r[4] >> 4)
};

// ---------------------------------------------------------------------------
// cross-lane xor exchange on one 32-bit value
// ---------------------------------------------------------------------------
template<int MASK>
__device__ __forceinline__ float swz(float v, int lane) {
    if constexpr (MASK == 1) {
        return __int_as_float(__builtin_amdgcn_mov_dpp(__float_as_int(v), 0xB1, 0xF, 0xF, true));
    } else if constexpr (MASK == 2) {
        return __int_as_float(__builtin_amdgcn_mov_dpp(__float_as_int(v), 0x4E, 0xF, 0xF, true));
    } else if constexpr (MASK == 3) {
        return __int_as_float(__builtin_amdgcn_mov_dpp(__float_as_int(v), 0x1B, 0xF, 0xF, true));
    } else if constexpr (MASK == 7) {
        return __int_as_float(__builtin_amdgcn_mov_dpp(__float_as_int(v), 0x141, 0xF, 0xF, true));
    } else if constexpr (MASK == 15) {
        return __int_as_float(__builtin_amdgcn_mov_dpp(__float_as_int(v), 0x140, 0xF, 0xF, true));
    } else if constexpr (MASK < 32) {
        return __int_as_float(__builtin_amdgcn_ds_swizzle(
            __float_as_int(v), (MASK << 10) | 0x1F));
    } else {
        return __int_as_float(__builtin_amdgcn_ds_bpermute(
            (lane << 2) ^ (MASK << 2), __float_as_int(v)));
    }
}

template<int MASK>
__device__ __forceinline__ v2 swz2(v2 v, int lane) {
    v2 r;
    r.x = swz<MASK>(v.x, lane);
    r.y = swz<MASK>(v.y, lane);
    return r;
}

__device__ __forceinline__ v2 mkv2(float a, float b) { v2 r; r.x = a; r.y = b; return r; }

__device__ __forceinline__ void cmul2(v2 ar, v2 ai, v2 br, v2 bi, v2& cr, v2& ci) {
    cr = ar * br - ai * bi;
    ci = ar * bi + ai * br;
}

// single amplitude-pair update; S (slot-role parity) folds at compile time.
__device__ __forceinline__ void upd(v2& xr, v2& xi, v2 pr, v2 pi,
                                    float cmr, float coi, float bmi, float bor,
                                    bool S) {
    const float emi = S ? -bmi : bmi;
    const float eor = S ? -bor : bor;
    const v2 nr = cmr * xr - emi * xi + eor * pr - coi * pi;
    const v2 ni = cmr * xi + emi * xr + eor * pi + coi * pr;
    xr = nr; xi = ni;
}

// one masked-pair rotation; SU(2): u11=conj(u00), u10=-conj(u01).
// coefficients come from the uniform ws pointer -> s_load_dwordx4 (SGPRs).
template<int G>
__device__ __forceinline__ void apply_rot(v2 (&sr)[16], v2 (&si)[16],
                                          const float4* __restrict__ ws,
                                          int lane) {
    constexpr unsigned pm = PL.pmask[G], rm = PL.rmask[G];
    constexpr int pLoc = pm & 15, pLane = (int)(pm >> 4);
    constexpr int rLoc = rm & 15, rLane = (int)(rm >> 4);
    const float4 m = ws[PL.lw[G]];                     // uniform -> scalar load
    const bool rl = (__popc(lane & rLane) & 1) != 0;   // lane part of role
    const float cmr = m.x, coi = m.w;
    const float bmi = rl ? -m.y : m.y;
    const float bor = rl ? -m.z : m.z;

    if constexpr (pLane == 0) {
        // fully local pair (j, j^pLoc)
#pragma unroll
        for (int j = 0; j < 16; ++j) {
            const int k = j ^ pLoc;
            if (j < k) {
                const v2 ajr = sr[j], aji = si[j];
                const v2 akr = sr[k], aki = si[k];
                upd(sr[j], si[j], akr, aki, cmr, coi, bmi, bor,
                    (__builtin_popcount(j & rLoc) & 1) != 0);
                upd(sr[k], si[k], ajr, aji, cmr, coi, bmi, bor,
                    (__builtin_popcount(k & rLoc) & 1) != 0);
            }
        }
    } else if constexpr (pLoc == 0) {
        // partner = same slot, other lane
#pragma unroll
        for (int j = 0; j < 16; ++j) {
            const v2 pr = swz2<pLane>(sr[j], lane);
            const v2 pi = swz2<pLane>(si[j], lane);
            upd(sr[j], si[j], pr, pi, cmr, coi, bmi, bor,
                (__builtin_popcount(j & rLoc) & 1) != 0);
        }
    } else {
        // partner = slot j^pLoc at lane^pLane
#pragma unroll
        for (int j = 0; j < 16; ++j) {
            const int k = j ^ pLoc;
            if (j < k) {
                const v2 pjr = swz2<pLane>(sr[k], lane);
                const v2 pji = swz2<pLane>(si[k], lane);
                const v2 pkr = swz2<pLane>(sr[j], lane);
                const v2 pki = swz2<pLane>(si[j], lane);
                upd(sr[j], si[j], pjr, pji, cmr, coi, bmi, bor,
                    (__builtin_popcount(j & rLoc) & 1) != 0);
                upd(sr[k], si[k], pkr, pki, cmr, coi, bmi, bor,
                    (__builtin_popcount(k & rLoc) & 1) != 0);
            }
        }
    }
}

template<int... Gs>
__device__ __forceinline__ void apply_all(v2 (&sr)[16], v2 (&si)[16],
                                          const float4* __restrict__ ws,
                                          int lane,
                                          std::integer_sequence<int, Gs...>) {
    (apply_rot<Gs>(sr, si, ws, lane), ...);
}

// ---- prep kernel: batch-uniform Rot coefficients -> d_ws (runs every call) ----
__global__ void prep_kernel(const float* __restrict__ W, float4* __restrict__ ws) {
    const int t = threadIdx.x;
    if (t < NL * NW) {
        const float phi = W[t * 3 + 0], th = W[t * 3 + 1], om = W[t * 3 + 2];
        float sh, ch; sincosf(0.5f * th, &sh, &ch);
        float s0, c0; sincosf(-0.5f * (phi + om), &s0, &c0);   // e^{-i(phi+om)/2}
        float s1, c1; sincosf( 0.5f * (phi - om), &s1, &c1);   // e^{+i(phi-om)/2}
        ws[t] = make_float4(c0 * ch, s0 * ch, -c1 * sh, -s1 * sh);
    }
}

__global__ __launch_bounds__(256, 2) void vqc_kernel(const float* __restrict__ X,
                                                     const float4* __restrict__ ws,
                                                     const float* __restrict__ bias,
                                                     float* __restrict__ out,
                                                     int n_pairs) {
    const int t = threadIdx.x;
    const int wave = (blockIdx.x * blockDim.x + t) >> 6;   // one wave per SAMPLE PAIR
    const int lane = t & 63;
    if (wave >= n_pairs) return;

    // ---- product-state init for both samples: v_w = Rot0_w * RY(x_w*pi/2)|0> ----
    // amplitude at physical p = psi_{R(p)}: lane wires select via parity masks
    const float* xp = X + (size_t)(2 * wave) * NW;        // sample0; sample1 at +NW

    // running lane-product H over wires 0..5 (parity-select per relabeling)
    v2 hr, hi;
#pragma unroll
    for (int w = 0; w < 6; ++w) {
        float s0, c0, s1, c1;
        __sincosf(xp[w]      * 0.78539816339744831f, &s0, &c0);
        __sincosf(xp[w + NW] * 0.78539816339744831f, &s1, &c1);
        const v2 s = mkv2(s0, s1), c = mkv2(c0, c1);
        const float4 m = ws[w];                            // layer 0 (scalar load)
        const v2 a0r = m.x * c + m.z * s;
        const v2 a0i = m.y * c + m.w * s;
        const v2 a1r = m.x * s - m.z * c;
        const v2 a1i = m.w * c - m.y * s;
        const bool b = (__popc(lane & LSEL[w]) & 1) != 0;
        const v2 br = b ? a1r : a0r;
        const v2 bi = b ? a1i : a0i;
        if (w == 0) { hr = br; hi = bi; }
        else {
            v2 nr, ni; cmul2(hr, hi, br, bi, nr, ni);
            hr = nr; hi = ni;
        }
    }
    // wires 6..9 (slot bits identity under T): local tables
    v2 t0r[4], t0i[4], t1r[4], t1i[4];
#pragma unroll
    for (int w = 6; w < 10; ++w) {
        float s0, c0, s1, c1;
        __sincosf(xp[w]      * 0.78539816339744831f, &s0, &c0);
        __sincosf(xp[w + NW] * 0.78539816339744831f, &s1, &c1);
        const v2 s = mkv2(s0, s1), c = mkv2(c0, c1);
        const float4 m = ws[w];
        t0r[w - 6] = m.x * c + m.z * s;
        t0i[w - 6] = m.y * c + m.w * s;
        t1r[w - 6] = m.x * s - m.z * c;
        t1i[w - 6] = m.w * c - m.y * s;
    }
    // A over wires 6,7 (slot bits 3,2), B over wires 8,9 (slot bits 1,0)
    v2 Ar[4], Ai[4], Br[4], Bi[4];
#pragma unroll
    for (int u = 0; u < 4; ++u) {
        const int hb = (u >> 1) & 1, lb = u & 1;
        cmul2(hb ? t1r[0] : t0r[0], hb ? t1i[0] : t0i[0],
              lb ? t1r[1] : t0r[1], lb ? t1i[1] : t0i[1], Ar[u], Ai[u]);
        cmul2(hb ? t1r[2] : t0r[2], hb ? t1i[2] : t0i[2],
              lb ? t1r[3] : t0r[3], lb ? t1i[3] : t0i[3], Br[u], Bi[u]);
    }
    // HA = H*A, then state[j] = HA[j>>2] * B[j&3]
    v2 HAr[4], HAi[4];
#pragma unroll
    for (int u = 0; u < 4; ++u) cmul2(hr, hi, Ar[u], Ai[u], HAr[u], HAi[u]);

    v2 sr[16], si[16];
#pragma unroll
    for (int j = 0; j < 16; ++j) {
        cmul2(HAr[j >> 2], HAi[j >> 2], Br[j & 3], Bi[j & 3], sr[j], si[j]);
    }

    // ---- 22 surviving rotations (layers 1..3), engine-interleaved order ----
    apply_all(sr, si, ws, lane, std::make_integer_sequence<int, NROT>{});

    // ---- measurement: sign = parity(p_phys & measmask) ----
    constexpr unsigned mm = PL.measmask;
    constexpr int mLoc = mm & 15, mLane = (int)(mm >> 4);
    v2 acc = mkv2(0.0f, 0.0f);
#pragma unroll
    for (int j = 0; j < 16; ++j) {
        const v2 p = sr[j] * sr[j] + si[j] * si[j];
        if (__builtin_popcount(j & mLoc) & 1) acc -= p; else acc += p;
    }
    if (__popc(lane & mLane) & 1) acc = -acc;
    acc += swz2<1>(acc, lane);
    acc += swz2<2>(acc, lane);
    acc += swz2<4>(acc, lane);
    acc += swz2<8>(acc, lane);
    acc += swz2<16>(acc, lane);
    acc += swz2<32>(acc, lane);
    if (lane == 0) {
        const float b0 = bias[0];
        out[2 * wave]     = acc.x + b0;
        out[2 * wave + 1] = acc.y + b0;
    }
}

extern "C" void kernel_launch(void* const* d_in, const int* in_sizes, int n_in,
                              void* d_out, int out_size, void* d_ws, size_t ws_size,
                              hipStream_t stream) {
    const float* X    = (const float*)d_in[0];
    const float* W    = (const float*)d_in[1];
    const float* bias = (const float*)d_in[2];
    float* out = (float*)d_out;
    float4* ws = (float4*)d_ws;                           // 40 x float4 = 640 B
    const int n_samples = in_sizes[0] / NW;               // 16384
    const int n_pairs = n_samples / 2;                    // 8192 (even batch)
    const int threads = 256;                              // 4 waves/block
    const int blocks = (n_pairs * 64 + threads - 1) / threads;
    hipLaunchKernelGGL(prep_kernel, dim3(1), dim3(64), 0, stream, W, ws);
    hipLaunchKernelGGL(vqc_kernel, dim3(blocks), dim3(threads), 0, stream,
                       X, (const float4*)ws, bias, out, n_pairs);
}

// Round 2
// 122.965 us; speedup vs baseline: 1.0202x; 1.0202x over previous
//
#include <hip/hip_runtime.h>
#include <cstdint>
#include <utility>

#define NW 10
#define NL 4

// ============================================================================
// Round 16: single-kernel fusion of the r13/r14 champion (77.8 us vqc dispatch,
// 125.5 us end-to-end => ~47 us off-kernel overhead).
//  - prep_kernel ELIMINATED: lanes 0..39 compute one gate's float4 coefficients
//    in-wave (3x __sincosf, lane-parallel); each gate reads them via
//    v_readlane_b32 at compile-time lane index -> still SGPR operands,
//    no LDS, no second dispatch, no d_ws round trip.
//  - X loads via readfirstlane-uniformed pointer into a statically-indexed
//    array (SMEM/s_load candidate; removes 20 divergent VMEM ops/wave).
//  - Final cross-half reduce via readlane pair instead of 2x ds_bpermute.
//  - Everything else identical: GF(2) plan, lightcone, DPP/ds_swizzle
//    exchanges, sample-pair v2 packing, engine-interleaved gate order.
// ============================================================================

typedef float v2 __attribute__((ext_vector_type(2)));

// ---- compile-time GF(2) relabeling ----------------------------------------
struct Cols10 { unsigned c[10]; };
struct Rows10 { unsigned r[10]; };

constexpr Cols10 TMAT = {{
    0x001, 0x002, 0x004, 0x008,                  // logical 0..3 -> slot bits
    0x070, 0x080, 0x100, 0x130, 0x210, 0x200     // logical 4..9 -> lane mixes
}};

constexpr unsigned tmap(unsigned m) {
    unsigned r = 0;
    for (int b = 0; b < 10; ++b) if ((m >> b) & 1u) r ^= TMAT.c[b];
    return r;
}

constexpr Rows10 invertT() {
    unsigned a[10] = {}, inv[10] = {};
    for (int i = 0; i < 10; ++i) {
        for (int j = 0; j < 10; ++j) a[i] |= ((TMAT.c[j] >> i) & 1u) << j;
        inv[i] = 1u << i;
    }
    for (int col = 0; col < 10; ++col) {
        int piv = -1;
        for (int r2 = col; r2 < 10; ++r2) if ((a[r2] >> col) & 1u) { piv = r2; break; }
        unsigned ta = a[piv]; a[piv] = a[col]; a[col] = ta;
        unsigned ti = inv[piv]; inv[piv] = inv[col]; inv[col] = ti;
        for (int r2 = 0; r2 < 10; ++r2)
            if (r2 != col && ((a[r2] >> col) & 1u)) { a[r2] ^= a[col]; inv[r2] ^= inv[col]; }
    }
    Rows10 R{};
    for (int i = 0; i < 10; ++i) R.r[i] = inv[i];
    return R;
}
constexpr Rows10 RROW = invertT();

constexpr unsigned rmap(unsigned rowmask) {
    unsigned r = 0;
    for (int b = 0; b < 10; ++b) if ((rowmask >> b) & 1u) r ^= RROW.r[b];
    return r;
}

static_assert(RROW.r[0] == 1 && RROW.r[1] == 2 && RROW.r[2] == 4 && RROW.r[3] == 8, "slot rows");
static_assert((RROW.r[4] & 15) == 0 && (RROW.r[5] & 15) == 0 && (RROW.r[6] & 15) == 0 &&
              (RROW.r[7] & 15) == 0 && (RROW.r[8] & 15) == 0 && (RROW.r[9] & 15) == 0, "lane rows");

struct Plan {
    int n;
    uint16_t pmask[40];
    uint16_t rmask[40];
    uint8_t  lw[40];
    uint16_t measmask;
};

constexpr bool keep_rot(int l, int w) {
    if (l <= 1) return true;
    if (l == 2) return w != 7;
    return w == 1 || w == 5 || w == 9;   // l == 3
}

constexpr int engine_class(unsigned pm) {    // 0 = local, 1 = DPP, 2 = DS
    const unsigned lm = pm >> 4;
    if (lm == 0) return 0;
    if (lm == 1 || lm == 2 || lm == 3 || lm == 7 || lm == 15) return 1;
    return 2;
}

constexpr Plan make_plan() {
    Plan P{};
    unsigned row[10], cI[10];
    for (int b = 0; b < 10; ++b) { row[b] = 1u << b; cI[b] = 1u << b; }
    P.n = 0;
    for (int l = 0; l < NL; ++l) {
        unsigned pm[10] = {}, rm[10] = {};
        int lw[10] = {}, cls[10] = {}, cnt = 0;
        for (int w = 0; w < NW; ++w) {
            if (l > 0 && keep_rot(l, w)) {
                const int b = 9 - w;
                pm[cnt] = tmap(cI[b]);
                rm[cnt] = rmap(row[b]);
                lw[cnt] = l * NW + w;
                cls[cnt] = engine_class(pm[cnt]);
                cnt++;
            }
        }
        // interleave DS gates with non-DS gates (alternating pipe bursts)
        int dsIdx[10] = {}, otIdx[10] = {};
        int nds = 0, not_ = 0;
        for (int i = 0; i < cnt; ++i) {
            if (cls[i] == 2) dsIdx[nds++] = i; else otIdx[not_++] = i;
        }
        int di = 0, oi = 0;
        while (di < nds || oi < not_) {
            if (di < nds) {
                const int i = dsIdx[di++];
                P.pmask[P.n] = (uint16_t)pm[i];
                P.rmask[P.n] = (uint16_t)rm[i];
                P.lw[P.n]    = (uint8_t)lw[i];
                P.n++;
            }
            if (oi < not_) {
                const int i = otIdx[oi++];
                P.pmask[P.n] = (uint16_t)pm[i];
                P.rmask[P.n] = (uint16_t)rm[i];
                P.lw[P.n]    = (uint8_t)lw[i];
                P.n++;
            }
        }
        const int r = l % (NW - 1) + 1;
        for (int w = 0; w < NW; ++w) {              // ring: CNOT(w, (w+r)%10)
            const int cb = 9 - w, tb = 9 - ((w + r) % NW);
            row[tb] ^= row[cb];                     // M <- C * M
            cI[cb]  ^= cI[tb];                      // Minv <- Minv * C
        }
    }
    P.measmask = (uint16_t)rmap(row[0]);            // Z on virtual bit 0 (wire 9)
    return P;
}

constexpr Plan PL = make_plan();
constexpr int NROT = 22;
static_assert(PL.n == NROT, "plan size mismatch");

constexpr int LSEL[6] = {
    (int)(RROW.r[9] >> 4), (int)(RROW.r[8] >> 4), (int)(RROW.r[7] >> 4),
    (int)(RROW.r[6] >> 4), (int)(RROW.r[5] >> 4), (int)(RROW.r[4] >> 4)
};

// ---------------------------------------------------------------------------
// cross-lane xor exchange on one 32-bit value
// ---------------------------------------------------------------------------
template<int MASK>
__device__ __forceinline__ float swz(float v, int lane) {
    if constexpr (MASK == 1) {
        return __int_as_float(__builtin_amdgcn_mov_dpp(__float_as_int(v), 0xB1, 0xF, 0xF, true));
    } else if constexpr (MASK == 2) {
        return __int_as_float(__builtin_amdgcn_mov_dpp(__float_as_int(v), 0x4E, 0xF, 0xF, true));
    } else if constexpr (MASK == 3) {
        return __int_as_float(__builtin_amdgcn_mov_dpp(__float_as_int(v), 0x1B, 0xF, 0xF, true));
    } else if constexpr (MASK == 7) {
        return __int_as_float(__builtin_amdgcn_mov_dpp(__float_as_int(v), 0x141, 0xF, 0xF, true));
    } else if constexpr (MASK == 15) {
        return __int_as_float(__builtin_amdgcn_mov_dpp(__float_as_int(v), 0x140, 0xF, 0xF, true));
    } else if constexpr (MASK < 32) {
        return __int_as_float(__builtin_amdgcn_ds_swizzle(
            __float_as_int(v), (MASK << 10) | 0x1F));
    } else {
        return __int_as_float(__builtin_amdgcn_ds_bpermute(
            (lane << 2) ^ (MASK << 2), __float_as_int(v)));
    }
}

template<int MASK>
__device__ __forceinline__ v2 swz2(v2 v, int lane) {
    v2 r;
    r.x = swz<MASK>(v.x, lane);
    r.y = swz<MASK>(v.y, lane);
    return r;
}

__device__ __forceinline__ v2 mkv2(float a, float b) { v2 r; r.x = a; r.y = b; return r; }

__device__ __forceinline__ float rdl(float v, int srclane) {
    return __int_as_float(__builtin_amdgcn_readlane(__float_as_int(v), srclane));
}

__device__ __forceinline__ void cmul2(v2 ar, v2 ai, v2 br, v2 bi, v2& cr, v2& ci) {
    cr = ar * br - ai * bi;
    ci = ar * bi + ai * br;
}

// single amplitude-pair update; S (slot-role parity) folds at compile time.
__device__ __forceinline__ void upd(v2& xr, v2& xi, v2 pr, v2 pi,
                                    float cmr, float coi, float bmi, float bor,
                                    bool S) {
    const float emi = S ? -bmi : bmi;
    const float eor = S ? -bor : bor;
    const v2 nr = cmr * xr - emi * xi + eor * pr - coi * pi;
    const v2 ni = cmr * xi + emi * xr + eor * pi + coi * pr;
    xr = nr; xi = ni;
}

// one masked-pair rotation; SU(2): u11=conj(u00), u10=-conj(u01).
// coefficients fetched from the prep lanes via v_readlane -> SGPRs.
template<int G>
__device__ __forceinline__ void apply_rot(v2 (&sr)[16], v2 (&si)[16],
                                          float cfx, float cfy, float cfz, float cfw,
                                          int lane) {
    constexpr unsigned pm = PL.pmask[G], rm = PL.rmask[G];
    constexpr int pLoc = pm & 15, pLane = (int)(pm >> 4);
    constexpr int rLoc = rm & 15, rLane = (int)(rm >> 4);
    constexpr int gl = PL.lw[G];                       // source lane (compile-time)
    const float cmr = rdl(cfx, gl);
    const float myy = rdl(cfy, gl);
    const float mzz = rdl(cfz, gl);
    const float coi = rdl(cfw, gl);
    const bool rl = (__popc(lane & rLane) & 1) != 0;   // lane part of role
    const float bmi = rl ? -myy : myy;
    const float bor = rl ? -mzz : mzz;

    if constexpr (pLane == 0) {
        // fully local pair (j, j^pLoc)
#pragma unroll
        for (int j = 0; j < 16; ++j) {
            const int k = j ^ pLoc;
            if (j < k) {
                const v2 ajr = sr[j], aji = si[j];
                const v2 akr = sr[k], aki = si[k];
                upd(sr[j], si[j], akr, aki, cmr, coi, bmi, bor,
                    (__builtin_popcount(j & rLoc) & 1) != 0);
                upd(sr[k], si[k], ajr, aji, cmr, coi, bmi, bor,
                    (__builtin_popcount(k & rLoc) & 1) != 0);
            }
        }
    } else if constexpr (pLoc == 0) {
        // partner = same slot, other lane
#pragma unroll
        for (int j = 0; j < 16; ++j) {
            const v2 pr = swz2<pLane>(sr[j], lane);
            const v2 pi = swz2<pLane>(si[j], lane);
            upd(sr[j], si[j], pr, pi, cmr, coi, bmi, bor,
                (__builtin_popcount(j & rLoc) & 1) != 0);
        }
    } else {
        // partner = slot j^pLoc at lane^pLane
#pragma unroll
        for (int j = 0; j < 16; ++j) {
            const int k = j ^ pLoc;
            if (j < k) {
                const v2 pjr = swz2<pLane>(sr[k], lane);
                const v2 pji = swz2<pLane>(si[k], lane);
                const v2 pkr = swz2<pLane>(sr[j], lane);
                const v2 pki = swz2<pLane>(si[j], lane);
                upd(sr[j], si[j], pjr, pji, cmr, coi, bmi, bor,
                    (__builtin_popcount(j & rLoc) & 1) != 0);
                upd(sr[k], si[k], pkr, pki, cmr, coi, bmi, bor,
                    (__builtin_popcount(k & rLoc) & 1) != 0);
            }
        }
    }
}

template<int... Gs>
__device__ __forceinline__ void apply_all(v2 (&sr)[16], v2 (&si)[16],
                                          float cfx, float cfy, float cfz, float cfw,
                                          int lane,
                                          std::integer_sequence<int, Gs...>) {
    (apply_rot<Gs>(sr, si, cfx, cfy, cfz, cfw, lane), ...);
}

__global__ __launch_bounds__(256, 2) void vqc_kernel(const float* __restrict__ X,
                                                     const float* __restrict__ W,
                                                     const float* __restrict__ bias,
                                                     float* __restrict__ out,
                                                     int n_pairs) {
    const int t = threadIdx.x;
    const int wave = (blockIdx.x * blockDim.x + t) >> 6;   // one wave per SAMPLE PAIR
    const int lane = t & 63;
    if (wave >= n_pairs) return;

    // ---- in-wave coefficient prep (lanes 0..39 each own one gate) ----------
    // Rot(phi,th,om): u00 = e^{-i(phi+om)/2} cos(th/2), u01 = -e^{i(phi-om)/2} sin(th/2)
    // packed as (cfx,cfy,cfz,cfw) = (Re u00, Im u00, Re u01, Im u01)
    float cfx, cfy, cfz, cfw;
    {
        const int g = (lane < NL * NW) ? lane : 0;
        const float phi = W[g * 3 + 0], th = W[g * 3 + 1], om = W[g * 3 + 2];
        float sh, ch; __sincosf(0.5f * th, &sh, &ch);
        float s0, c0; __sincosf(-0.5f * (phi + om), &s0, &c0);   // e^{-i(phi+om)/2}
        float s1, c1; __sincosf( 0.5f * (phi - om), &s1, &c1);   // e^{+i(phi-om)/2}
        cfx = c0 * ch; cfy = s0 * ch; cfz = -c1 * sh; cfw = -s1 * sh;
    }

    // ---- wave-uniform X pointer -> scalar-load candidates ------------------
    const uintptr_t pbits = (uintptr_t)(X + (size_t)(2 * wave) * NW);
    const float* xp = (const float*)(
        ((uintptr_t)(uint32_t)__builtin_amdgcn_readfirstlane((uint32_t)(pbits >> 32)) << 32) |
        (uintptr_t)(uint32_t)__builtin_amdgcn_readfirstlane((uint32_t)pbits));
    float xv[2 * NW];
#pragma unroll
    for (int i = 0; i < 2 * NW; ++i) xv[i] = xp[i];

    // ---- product-state init for both samples: v_w = Rot0_w * RY(x_w*pi/2)|0> ----
    // running lane-product H over wires 0..5 (parity-select per relabeling)
    v2 hr, hi;
#pragma unroll
    for (int w = 0; w < 6; ++w) {
        float s0, c0, s1, c1;
        __sincosf(xv[w]      * 0.78539816339744831f, &s0, &c0);
        __sincosf(xv[w + NW] * 0.78539816339744831f, &s1, &c1);
        const v2 s = mkv2(s0, s1), c = mkv2(c0, c1);
        const float mx = rdl(cfx, w), my = rdl(cfy, w);
        const float mz = rdl(cfz, w), mw = rdl(cfw, w);
        const v2 a0r = mx * c + mz * s;
        const v2 a0i = my * c + mw * s;
        const v2 a1r = mx * s - mz * c;
        const v2 a1i = mw * c - my * s;
        const bool b = (__popc(lane & LSEL[w]) & 1) != 0;
        const v2 br = b ? a1r : a0r;
        const v2 bi = b ? a1i : a0i;
        if (w == 0) { hr = br; hi = bi; }
        else {
            v2 nr, ni; cmul2(hr, hi, br, bi, nr, ni);
            hr = nr; hi = ni;
        }
    }
    // wires 6..9 (slot bits identity under T): local tables
    v2 t0r[4], t0i[4], t1r[4], t1i[4];
#pragma unroll
    for (int w = 6; w < 10; ++w) {
        float s0, c0, s1, c1;
        __sincosf(xv[w]      * 0.78539816339744831f, &s0, &c0);
        __sincosf(xv[w + NW] * 0.78539816339744831f, &s1, &c1);
        const v2 s = mkv2(s0, s1), c = mkv2(c0, c1);
        const float mx = rdl(cfx, w), my = rdl(cfy, w);
        const float mz = rdl(cfz, w), mw = rdl(cfw, w);
        t0r[w - 6] = mx * c + mz * s;
        t0i[w - 6] = my * c + mw * s;
        t1r[w - 6] = mx * s - mz * c;
        t1i[w - 6] = mw * c - my * s;
    }
    // A over wires 6,7 (slot bits 3,2), B over wires 8,9 (slot bits 1,0)
    v2 Ar[4], Ai[4], Br[4], Bi[4];
#pragma unroll
    for (int u = 0; u < 4; ++u) {
        const int hb = (u >> 1) & 1, lb = u & 1;
        cmul2(hb ? t1r[0] : t0r[0], hb ? t1i[0] : t0i[0],
              lb ? t1r[1] : t0r[1], lb ? t1i[1] : t0i[1], Ar[u], Ai[u]);
        cmul2(hb ? t1r[2] : t0r[2], hb ? t1i[2] : t0i[2],
              lb ? t1r[3] : t0r[3], lb ? t1i[3] : t0i[3], Br[u], Bi[u]);
    }
    // HA = H*A, then state[j] = HA[j>>2] * B[j&3]
    v2 HAr[4], HAi[4];
#pragma unroll
    for (int u = 0; u < 4; ++u) cmul2(hr, hi, Ar[u], Ai[u], HAr[u], HAi[u]);

    v2 sr[16], si[16];
#pragma unroll
    for (int j = 0; j < 16; ++j) {
        cmul2(HAr[j >> 2], HAi[j >> 2], Br[j & 3], Bi[j & 3], sr[j], si[j]);
    }

    // ---- 22 surviving rotations (layers 1..3), engine-interleaved order ----
    apply_all(sr, si, cfx, cfy, cfz, cfw, lane,
              std::make_integer_sequence<int, NROT>{});

    // ---- measurement: sign = parity(p_phys & measmask) ----
    constexpr unsigned mm = PL.measmask;
    constexpr int mLoc = mm & 15, mLane = (int)(mm >> 4);
    v2 acc = mkv2(0.0f, 0.0f);
#pragma unroll
    for (int j = 0; j < 16; ++j) {
        const v2 p = sr[j] * sr[j] + si[j] * si[j];
        if (__builtin_popcount(j & mLoc) & 1) acc -= p; else acc += p;
    }
    if (__popc(lane & mLane) & 1) acc = -acc;
    acc += swz2<1>(acc, lane);
    acc += swz2<2>(acc, lane);
    acc += swz2<4>(acc, lane);
    acc += swz2<8>(acc, lane);
    acc += swz2<16>(acc, lane);
    // cross-half sum via readlane (replaces 2x ds_bpermute)
    const float sx = rdl(acc.x, 0) + rdl(acc.x, 32);
    const float sy = rdl(acc.y, 0) + rdl(acc.y, 32);
    if (lane == 0) {
        const float b0 = bias[0];
        out[2 * wave]     = sx + b0;
        out[2 * wave + 1] = sy + b0;
    }
}

extern "C" void kernel_launch(void* const* d_in, const int* in_sizes, int n_in,
                              void* d_out, int out_size, void* d_ws, size_t ws_size,
                              hipStream_t stream) {
    const float* X    = (const float*)d_in[0];
    const float* W    = (const float*)d_in[1];
    const float* bias = (const float*)d_in[2];
    float* out = (float*)d_out;
    const int n_samples = in_sizes[0] / NW;               // 16384
    const int n_pairs = n_samples / 2;                    // 8192 (even batch)
    const int threads = 256;                              // 4 waves/block
    const int blocks = (n_pairs * 64 + threads - 1) / threads;
    hipLaunchKernelGGL(vqc_kernel, dim3(blocks), dim3(threads), 0, stream,
                       X, W, bias, out, n_pairs);
}